// Round 1
// baseline (1196.290 us; speedup 1.0000x reference)
//
#include <hip/hip_runtime.h>
#include <math.h>

#define NVOCAB 50000
#define NE 256
#define NS 512
#define NB 4
#define NT 2048

// workspace float offsets
#define OFF_G     0
#define OFF_GMAT  256
#define OFF_CW1   (OFF_GMAT + 65536)
#define OFF_DW1   (OFF_CW1 + 65536)
#define OFF_XS    (OFF_DW1 + 131072)
#define OFF_H2    (OFF_XS + 524288)
#define OFF_CA    (OFF_H2 + 524288)
// total floats: OFF_CA + 128 = 1311104  (~5.25 MB)

__device__ __forceinline__ float gelu_exact(float x) {
  return 0.5f * x * (1.0f + erff(x * 0.70710678118654752440f));
}

// --- prep1: spectral kernel g[256] + zero concept accumulator ---
__global__ __launch_bounds__(256) void k_prep1(float* ws) {
  int t = threadIdx.x;
  if (blockIdx.x == 0) {
    // g[t] = (1/256) sum_m c4[m] * cos(2*pi*m*t/256), c4[m]=cos(1.5*atan(ln(4*min(m,256-m)+1e-6)))
    float sum = 0.f;
    for (int m = 0; m < 256; m++) {
      int mm = (m <= 128) ? m : (256 - m);
      float c = cosf(1.5f * atanf(logf(4.0f * (float)mm + 1e-6f)));
      int r = (m * t) & 255;           // exact periodic reduction -> tiny args for cosf
      sum += c * cosf((float)r * (6.283185307179586f / 256.0f));
    }
    ws[OFF_G + t] = sum * (1.0f / 256.0f);
  } else {
    if (t < 128) ws[OFF_CA + t] = 0.0f;
  }
}

// --- prep2: Gmat[d][t] = g[(t-d)&255]; effective (block-summed) cw1/dw1 ---
__global__ __launch_bounds__(256) void k_prep2(const float* cw1, const float* dw1, float* ws) {
  int b = blockIdx.x, t = threadIdx.x;
  if (b < 256) {
    int d = b;
    ws[OFF_GMAT + d * 256 + t] = ws[OFF_G + ((t - d) & 255)];
  } else if (b < 512) {
    int r = b - 256;
    float s = 0.f;
    #pragma unroll
    for (int q = 0; q < 4; q++) s += cw1[(q * 256 + r) * 256 + t];
    ws[OFF_CW1 + r * 256 + t] = s;
  } else {
    int idx = (b - 512) * 256 + t;   // 0..131071
    int r = idx >> 9, c = idx & 511;
    float s = 0.f;
    #pragma unroll
    for (int q = 0; q < 4; q++) s += dw1[(q * 256 + r) * 512 + c];
    ws[OFF_DW1 + idx] = s;
  }
}

// --- spectral: xs[i][t] = (sum_d |x[i][d]| * Gmat[d][t]) * sign(x[i][t]) ---
__global__ __launch_bounds__(256) void k_spectral(const int* ids, const float* emb, float* ws) {
  __shared__ __align__(16) float xb[8][256];
  int t = threadIdx.x;
  int i0 = blockIdx.x * 8;
  #pragma unroll
  for (int rr = 0; rr < 8; rr++) {
    int id = ids[i0 + rr];
    xb[rr][t] = emb[id * 256 + t];
  }
  __syncthreads();
  float acc[8] = {0, 0, 0, 0, 0, 0, 0, 0};
  const float* Gm = ws + OFF_GMAT;
  for (int d = 0; d < 256; d += 4) {
    float w0 = Gm[(d + 0) * 256 + t];
    float w1 = Gm[(d + 1) * 256 + t];
    float w2 = Gm[(d + 2) * 256 + t];
    float w3 = Gm[(d + 3) * 256 + t];
    #pragma unroll
    for (int rr = 0; rr < 8; rr++) {
      float4 a4 = *(const float4*)&xb[rr][d];
      acc[rr] += fabsf(a4.x) * w0 + fabsf(a4.y) * w1 + fabsf(a4.z) * w2 + fabsf(a4.w) * w3;
    }
  }
  #pragma unroll
  for (int rr = 0; rr < 8; rr++) {
    float x = xb[rr][t];
    float sg = (x > 0.f) ? 1.f : ((x < 0.f) ? -1.f : 0.f);
    ws[OFF_XS + (i0 + rr) * 256 + t] = acc[rr] * sg;
  }
}

// --- concept recognizer + per-block partial mean into accumulator ---
__global__ __launch_bounds__(256) void k_concept(const float* cb1, const float* cw2, const float* cb2,
                                                 const float* cw3, const float* cb3, float* ws) {
  __shared__ __align__(16) float xs_s[8][256];
  __shared__ __align__(16) float c1s[8][256];
  __shared__ float c2s[8][64];
  __shared__ float c3s[8][32];
  int t = threadIdx.x;
  int i0 = blockIdx.x * 8;
  #pragma unroll
  for (int rr = 0; rr < 8; rr++) xs_s[rr][t] = ws[OFF_XS + (i0 + rr) * 256 + t];
  __syncthreads();
  const float* cw1eff = ws + OFF_CW1;
  float acc[8] = {0, 0, 0, 0, 0, 0, 0, 0};
  for (int d = 0; d < 256; d += 4) {
    float w0 = cw1eff[(d + 0) * 256 + t];
    float w1 = cw1eff[(d + 1) * 256 + t];
    float w2 = cw1eff[(d + 2) * 256 + t];
    float w3 = cw1eff[(d + 3) * 256 + t];
    #pragma unroll
    for (int rr = 0; rr < 8; rr++) {
      float4 a4 = *(const float4*)&xs_s[rr][d];
      acc[rr] += a4.x * w0 + a4.y * w1 + a4.z * w2 + a4.w * w3;
    }
  }
  float b1v = cb1[t];
  #pragma unroll
  for (int rr = 0; rr < 8; rr++) c1s[rr][t] = fmaxf(acc[rr] + b1v, 0.f);
  __syncthreads();
  {
    int e = t & 63, grp = t >> 6;   // grp 0..3 -> rows 2*grp, 2*grp+1
    float a0 = 0.f, a1 = 0.f;
    for (int d = 0; d < 256; d++) {
      float w = cw2[d * 64 + e];
      a0 += c1s[grp * 2 + 0][d] * w;
      a1 += c1s[grp * 2 + 1][d] * w;
    }
    float b2v = cb2[e];
    c2s[grp * 2 + 0][e] = fmaxf(a0 + b2v, 0.f);
    c2s[grp * 2 + 1][e] = fmaxf(a1 + b2v, 0.f);
  }
  __syncthreads();
  {
    int v = t & 31, grp = t >> 5;   // grp 0..7 -> row grp
    float a = 0.f;
    for (int d = 0; d < 64; d++) a += c2s[grp][d] * cw3[d * 32 + v];
    c3s[grp][v] = a + cb3[v];
  }
  __syncthreads();
  if (t < 32) {
    float s = 0.f;
    #pragma unroll
    for (int rr = 0; rr < 8; rr++) s += c3s[rr][t];
    int bb = i0 >> 9;   // token / 512
    atomicAdd(ws + OFF_CA + bb * 32 + t, s * (1.0f / 512.0f));
  }
}

// --- structure generator (tiny) + emit concept_vector ---
__global__ __launch_bounds__(128) void k_structure(const float* sw1, const float* sb1,
                                                   const float* sw2, const float* sb2,
                                                   float* out, const float* ws) {
  __shared__ float cv[4][32];
  __shared__ float s1[4][16];
  int t = threadIdx.x;
  {
    int b = t >> 5, j = t & 31;
    float v = ws[OFF_CA + t];
    cv[b][j] = v;
    out[102400000 + t] = v;   // concept_vector [4,32]
  }
  __syncthreads();
  if (t < 64) {
    int b = t >> 4, e = t & 15;
    float a = sb1[e];
    for (int d = 0; d < 32; d++) a += cv[b][d] * sw1[d * 16 + e];
    s1[b][e] = fmaxf(a, 0.f);
  }
  __syncthreads();
  if (t < 32) {
    int b = t >> 3, e = t & 7;
    float a = sb2[e];
    for (int d = 0; d < 16; d++) a += s1[b][d] * sw2[d * 8 + e];
    out[102400128 + t] = 1.0f / (1.0f + expf(-a));   // structure_probs [4,8]
  }
}

// --- decoder mid: h1 = gelu(xs@DW1eff+db1); LN; h2 = gelu(h1@dw2+db2) ---
__global__ __launch_bounds__(256) void k_decoder(const float* db1, const float* lng, const float* lnb,
                                                 const float* dw2, const float* db2, float* ws) {
  __shared__ __align__(16) float xs_s[8][256];
  __shared__ __align__(16) float h1s[8][512];
  __shared__ float mu_s[8], rs_s[8];
  int t = threadIdx.x;
  int i0 = blockIdx.x * 8;
  #pragma unroll
  for (int rr = 0; rr < 8; rr++) xs_s[rr][t] = ws[OFF_XS + (i0 + rr) * 256 + t];
  __syncthreads();
  const float* dw1eff = ws + OFF_DW1;
  float a1[8] = {0, 0, 0, 0, 0, 0, 0, 0};
  float a2[8] = {0, 0, 0, 0, 0, 0, 0, 0};
  for (int d = 0; d < 256; d += 2) {
    float wa0 = dw1eff[(d + 0) * 512 + t];
    float wb0 = dw1eff[(d + 0) * 512 + t + 256];
    float wa1 = dw1eff[(d + 1) * 512 + t];
    float wb1 = dw1eff[(d + 1) * 512 + t + 256];
    #pragma unroll
    for (int rr = 0; rr < 8; rr++) {
      float2 x2 = *(const float2*)&xs_s[rr][d];
      a1[rr] += x2.x * wa0 + x2.y * wa1;
      a2[rr] += x2.x * wb0 + x2.y * wb1;
    }
  }
  float ba = db1[t], bb = db1[t + 256];
  #pragma unroll
  for (int rr = 0; rr < 8; rr++) {
    h1s[rr][t]       = gelu_exact(a1[rr] + ba);
    h1s[rr][t + 256] = gelu_exact(a2[rr] + bb);
  }
  __syncthreads();
  {
    int rr = t >> 5, q = t & 31;   // 8 rows x 32 threads
    float sum = 0.f, sq = 0.f;
    for (int j = q; j < 512; j += 32) {
      float v = h1s[rr][j];
      sum += v; sq += v * v;
    }
    #pragma unroll
    for (int off = 16; off >= 1; off >>= 1) {
      sum += __shfl_down(sum, off, 32);
      sq  += __shfl_down(sq, off, 32);
    }
    if (q == 0) {
      float mu = sum * (1.0f / 512.0f);
      float var = sq * (1.0f / 512.0f) - mu * mu;
      mu_s[rr] = mu;
      rs_s[rr] = rsqrtf(var + 1e-5f);
    }
  }
  __syncthreads();
  {
    float ga = lng[t], bba = lnb[t], gb = lng[t + 256], bbb = lnb[t + 256];
    #pragma unroll
    for (int rr = 0; rr < 8; rr++) {
      float m = mu_s[rr], r = rs_s[rr];
      h1s[rr][t]       = (h1s[rr][t]       - m) * r * ga + bba;
      h1s[rr][t + 256] = (h1s[rr][t + 256] - m) * r * gb + bbb;
    }
  }
  __syncthreads();
  float acc[8] = {0, 0, 0, 0, 0, 0, 0, 0};
  for (int d = 0; d < 512; d += 2) {
    float w0 = dw2[(d + 0) * 256 + t];
    float w1 = dw2[(d + 1) * 256 + t];
    #pragma unroll
    for (int rr = 0; rr < 8; rr++) {
      float2 h2v = *(const float2*)&h1s[rr][d];
      acc[rr] += h2v.x * w0 + h2v.y * w1;
    }
  }
  float b2v = db2[t];
  #pragma unroll
  for (int rr = 0; rr < 8; rr++)
    ws[OFF_H2 + (i0 + rr) * 256 + t] = gelu_exact(acc[rr] + b2v);
}

// --- logits: C[2048,50000] = h2[2048,256] @ dw3[256,50000] + db3 (fp32) ---
// 128x128 tile, BK=16, 256 threads, 8x8 microtile. A stored k-major in LDS.
__global__ __launch_bounds__(256) void k_logits(const float* dw3, const float* db3,
                                                float* out, const float* ws) {
  __shared__ __align__(16) float As[16 * 128];
  __shared__ __align__(16) float Bs[16 * 128];
  int t = threadIdx.x;
  int n0 = blockIdx.x * 128;
  int m0 = blockIdx.y * 128;
  int tx = t & 15, ty = t >> 4;
  const float* h2 = ws + OFF_H2;

  float acc[8][8];
  #pragma unroll
  for (int i = 0; i < 8; i++)
    #pragma unroll
    for (int j = 0; j < 8; j++) acc[i][j] = 0.f;

  int ar = t >> 1, ah = t & 1;          // A: row ar (0..127), k-half ah
  int bk = t >> 4, bn = (t & 15) * 8;   // B: k-row bk (0..15), col offset bn
  bool bval = (n0 + bn) < NVOCAB;       // 50000 % 8 == 0 -> all-or-none chunks

  for (int k0 = 0; k0 < 256; k0 += 16) {
    float4 av0 = *(const float4*)&h2[(m0 + ar) * 256 + k0 + ah * 8];
    float4 av1 = *(const float4*)&h2[(m0 + ar) * 256 + k0 + ah * 8 + 4];
    float4 bv0, bv1;
    if (bval) {
      const float* bp = dw3 + (size_t)(k0 + bk) * NVOCAB + n0 + bn;
      bv0 = *(const float4*)bp;
      bv1 = *(const float4*)(bp + 4);
    } else {
      bv0 = make_float4(0.f, 0.f, 0.f, 0.f);
      bv1 = make_float4(0.f, 0.f, 0.f, 0.f);
    }
    __syncthreads();
    {
      int kb = ah * 8;
      As[(kb + 0) * 128 + ar] = av0.x;
      As[(kb + 1) * 128 + ar] = av0.y;
      As[(kb + 2) * 128 + ar] = av0.z;
      As[(kb + 3) * 128 + ar] = av0.w;
      As[(kb + 4) * 128 + ar] = av1.x;
      As[(kb + 5) * 128 + ar] = av1.y;
      As[(kb + 6) * 128 + ar] = av1.z;
      As[(kb + 7) * 128 + ar] = av1.w;
      *(float4*)&Bs[bk * 128 + bn] = bv0;
      *(float4*)&Bs[bk * 128 + bn + 4] = bv1;
    }
    __syncthreads();
    #pragma unroll
    for (int k = 0; k < 16; k++) {
      float4 a0 = *(const float4*)&As[k * 128 + ty * 4];
      float4 a1 = *(const float4*)&As[k * 128 + 64 + ty * 4];
      float4 b0 = *(const float4*)&Bs[k * 128 + tx * 4];
      float4 b1 = *(const float4*)&Bs[k * 128 + 64 + tx * 4];
      float am[8] = {a0.x, a0.y, a0.z, a0.w, a1.x, a1.y, a1.z, a1.w};
      float bm[8] = {b0.x, b0.y, b0.z, b0.w, b1.x, b1.y, b1.z, b1.w};
      #pragma unroll
      for (int i = 0; i < 8; i++)
        #pragma unroll
        for (int j = 0; j < 8; j++)
          acc[i][j] += am[i] * bm[j];
    }
  }
  #pragma unroll
  for (int jj = 0; jj < 2; jj++) {
    int nb = n0 + jj * 64 + tx * 4;
    if (nb < NVOCAB) {
      float4 bias = *(const float4*)&db3[nb];
      #pragma unroll
      for (int i = 0; i < 8; i++) {
        int m = m0 + (i < 4 ? ty * 4 + i : 64 + ty * 4 + (i - 4));
        float4 o;
        o.x = acc[i][jj * 4 + 0] + bias.x;
        o.y = acc[i][jj * 4 + 1] + bias.y;
        o.z = acc[i][jj * 4 + 2] + bias.z;
        o.w = acc[i][jj * 4 + 3] + bias.w;
        *(float4*)&out[(size_t)m * NVOCAB + nb] = o;
      }
    }
  }
}

extern "C" void kernel_launch(void* const* d_in, const int* in_sizes, int n_in,
                              void* d_out, int out_size, void* d_ws, size_t ws_size,
                              hipStream_t stream) {
  const int*   ids = (const int*)d_in[0];
  const float* emb = (const float*)d_in[1];
  const float* dw1 = (const float*)d_in[2];
  const float* db1 = (const float*)d_in[3];
  const float* lng = (const float*)d_in[4];
  const float* lnb = (const float*)d_in[5];
  const float* dw2 = (const float*)d_in[6];
  const float* db2 = (const float*)d_in[7];
  const float* dw3 = (const float*)d_in[8];
  const float* db3 = (const float*)d_in[9];
  const float* cw1 = (const float*)d_in[10];
  const float* cb1 = (const float*)d_in[11];
  const float* cw2 = (const float*)d_in[12];
  const float* cb2 = (const float*)d_in[13];
  const float* cw3 = (const float*)d_in[14];
  const float* cb3 = (const float*)d_in[15];
  const float* sw1 = (const float*)d_in[16];
  const float* sb1 = (const float*)d_in[17];
  const float* sw2 = (const float*)d_in[18];
  const float* sb2 = (const float*)d_in[19];
  float* out = (float*)d_out;
  float* ws  = (float*)d_ws;

  hipLaunchKernelGGL(k_prep1, dim3(2), dim3(256), 0, stream, ws);
  hipLaunchKernelGGL(k_prep2, dim3(1024), dim3(256), 0, stream, cw1, dw1, ws);
  hipLaunchKernelGGL(k_spectral, dim3(256), dim3(256), 0, stream, ids, emb, ws);
  hipLaunchKernelGGL(k_concept, dim3(256), dim3(256), 0, stream, cb1, cw2, cb2, cw3, cb3, ws);
  hipLaunchKernelGGL(k_structure, dim3(1), dim3(128), 0, stream, sw1, sb1, sw2, sb2, out, ws);
  hipLaunchKernelGGL(k_decoder, dim3(256), dim3(256), 0, stream, db1, lng, lnb, dw2, db2, ws);
  hipLaunchKernelGGL(k_logits, dim3(391, 16), dim3(256), 0, stream, dw3, db3, out, ws);
}